// Round 1
// baseline (446.100 us; speedup 1.0000x reference)
//
#include <hip/hip_runtime.h>
#include <hip/hip_bf16.h>
#include <math.h>

#define Tn 100
#define Bn 2048

__device__ __forceinline__ float sp_f(float x) {
    // jax.nn.softplus(x) = max(x,0) + log1p(exp(-|x|))
    float e = __expf(-fabsf(x));
    return fmaxf(x, 0.f) + __logf(1.f + e);
}
__device__ __forceinline__ float clamp6(float x) {
    return fminf(fmaxf(x, -6.f), 6.f);
}

// ---------------------------------------------------------------- encoder
// One thread per (tt,b) sample. e = L3(sp(L2(sp(L1(x))))), x = xs[tt][b][0:150].
// ctx[tt][b][:] = e[12:15]; for tt==0 also write qz0_mean/logstd = e[0:12].
__global__ __launch_bounds__(256) void enc_kernel(
    const float* __restrict__ xs,
    const float* __restrict__ eW1, const float* __restrict__ eb1,
    const float* __restrict__ eW2, const float* __restrict__ eb2,
    const float* __restrict__ eW3, const float* __restrict__ eb3,
    float* __restrict__ ctx, float* __restrict__ qm, float* __restrict__ qs)
{
    __shared__ float w[5925];
    for (int i = threadIdx.x; i < 4500; i += 256) w[i] = eW1[i];
    if (threadIdx.x < 30) w[4500 + threadIdx.x] = eb1[threadIdx.x];
    for (int i = threadIdx.x; i < 900; i += 256) w[4530 + i] = eW2[i];
    if (threadIdx.x < 30) w[5430 + threadIdx.x] = eb2[threadIdx.x];
    for (int i = threadIdx.x; i < 450; i += 256) w[5460 + i] = eW3[i];
    if (threadIdx.x < 15) w[5910 + threadIdx.x] = eb3[threadIdx.x];
    __syncthreads();

    int gid = blockIdx.x * 256 + threadIdx.x;          // = tt*Bn + b
    const float* x = xs + (size_t)gid * 150;

    float h1[30];
#pragma unroll
    for (int j = 0; j < 30; ++j) h1[j] = w[4500 + j];
    for (int i = 0; i < 150; i += 2) {
        float2 xv = *reinterpret_cast<const float2*>(x + i);
#pragma unroll
        for (int j = 0; j < 30; ++j) h1[j] = fmaf(xv.x, w[i * 30 + j], h1[j]);
#pragma unroll
        for (int j = 0; j < 30; ++j) h1[j] = fmaf(xv.y, w[(i + 1) * 30 + j], h1[j]);
    }
#pragma unroll
    for (int j = 0; j < 30; ++j) h1[j] = sp_f(h1[j]);

    float h2[30];
#pragma unroll
    for (int j = 0; j < 30; ++j) h2[j] = w[5430 + j];
    for (int j1 = 0; j1 < 30; ++j1) {
        float hv = h1[j1];
#pragma unroll
        for (int j = 0; j < 30; ++j) h2[j] = fmaf(hv, w[4530 + j1 * 30 + j], h2[j]);
    }
#pragma unroll
    for (int j = 0; j < 30; ++j) h2[j] = sp_f(h2[j]);

    float o12 = w[5910 + 12], o13 = w[5910 + 13], o14 = w[5910 + 14];
#pragma unroll
    for (int j2 = 0; j2 < 30; ++j2) {
        o12 = fmaf(h2[j2], w[5460 + j2 * 15 + 12], o12);
        o13 = fmaf(h2[j2], w[5460 + j2 * 15 + 13], o13);
        o14 = fmaf(h2[j2], w[5460 + j2 * 15 + 14], o14);
    }
    float* cp = ctx + (size_t)gid * 3;
    cp[0] = o12; cp[1] = o13; cp[2] = o14;

    if (blockIdx.x < 8) {   // tt == 0: qz0 stats (e[-1] of flipped == enc(xs[0]))
        int b = gid;
        float o[12];
#pragma unroll
        for (int j3 = 0; j3 < 12; ++j3) o[j3] = w[5910 + j3];
#pragma unroll
        for (int j2 = 0; j2 < 30; ++j2) {
            float hv = h2[j2];
#pragma unroll
            for (int j3 = 0; j3 < 12; ++j3) o[j3] = fmaf(hv, w[5460 + j2 * 15 + j3], o[j3]);
        }
#pragma unroll
        for (int d = 0; d < 6; ++d) { qm[b * 6 + d] = o[d]; qs[b * 6 + d] = o[6 + d]; }
    }
}

// ------------------------------------------- A_g precompute (t-dependent g bias)
// ag[k][d][jj] = gb1[d][jj] + ts[k] * gW1[d][0][jj]
__global__ void ag_kernel(const float* __restrict__ ts, const float* __restrict__ gW1,
                          const float* __restrict__ gb1, float* __restrict__ ag)
{
    int idx = blockIdx.x * 256 + threadIdx.x;
    if (idx >= (Tn - 1) * 180) return;
    int k = idx / 180, r = idx % 180;
    int d = r / 30, jj = r % 30;
    ag[idx] = fmaf(ts[k], gW1[d * 60 + jj], gb1[r]);
}

// ---------------------------------------------------------- z0 + KL reduction
__global__ __launch_bounds__(256) void z0kl_kernel(
    const float* __restrict__ qm, const float* __restrict__ qs,
    const float* __restrict__ eps0, const float* __restrict__ pm,
    const float* __restrict__ ps, float* __restrict__ zsb, float* __restrict__ acc)
{
    int idx = blockIdx.x * 256 + threadIdx.x;   // < Bn*6
    int d = idx % 6;
    float m = qm[idx], lsq = qs[idx];
    float sq = __expf(clamp6(lsq));
    zsb[idx] = fmaf(sq, eps0[idx], m);          // zs[0][b][d]
    float spz = __expf(clamp6(ps[d]));
    float dm = m - pm[d];
    float kl = __logf(spz / sq) + (sq * sq + dm * dm) / (2.f * spz * spz) - 0.5f;
#pragma unroll
    for (int mm = 1; mm <= 32; mm <<= 1) kl += __shfl_xor(kl, mm);
    __shared__ float red[4];
    if ((threadIdx.x & 63) == 0) red[threadIdx.x >> 6] = kl;
    __syncthreads();
    if (threadIdx.x == 0) atomicAdd(&acc[1], red[0] + red[1] + red[2] + red[3]);
}

// ------------------------------------------------------------------- SDE scan
// 8 lanes per batch element; block = 64 threads (one wave, no barriers);
// grid = 256 blocks covers B=2048. All f/h weights + own g-column in VGPRs.
__global__ __launch_bounds__(64, 1) void scan_kernel(
    const float* __restrict__ ts, const float* __restrict__ dWall,
    const float* __restrict__ fW1, const float* __restrict__ fb1,
    const float* __restrict__ fW2, const float* __restrict__ fb2,
    const float* __restrict__ hW1, const float* __restrict__ hb1,
    const float* __restrict__ hW2, const float* __restrict__ hb2,
    const float* __restrict__ gW1, const float* __restrict__ gW2,
    const float* __restrict__ gb2,
    const float* __restrict__ ctx, const float* __restrict__ ag,
    float* __restrict__ zsb, float* __restrict__ acc)
{
    int tid = threadIdx.x;
    int q = tid & 7;
    int b = blockIdx.x * 8 + (tid >> 3);

    // --- per-lane weight registers -------------------------------------
    float wf[10][4], fb1v[4], wh[7][4], hb1v[4], wf2[4][6], wh2[4][6];
#pragma unroll
    for (int r = 0; r < 4; ++r) {
        int j = q + 8 * r;
        bool v = j < 30;
        fb1v[r] = v ? fb1[j] : 0.f;
        hb1v[r] = v ? hb1[j] : 0.f;
#pragma unroll
        for (int i = 0; i < 10; ++i) wf[i][r] = v ? fW1[i * 30 + j] : 0.f;
#pragma unroll
        for (int i = 0; i < 7; ++i) wh[i][r] = v ? hW1[i * 30 + j] : 0.f;
#pragma unroll
        for (int d = 0; d < 6; ++d) {
            wf2[r][d] = v ? fW2[j * 6 + d] : 0.f;
            wh2[r][d] = v ? hW2[j * 6 + d] : 0.f;
        }
    }
    float fb2v[6], hb2v[6];
#pragma unroll
    for (int d = 0; d < 6; ++d) { fb2v[d] = fb2[d]; hb2v[d] = hb2[d]; }
    int dd = (q < 6) ? q : 0;
    float w1b[30], wg2[30];
#pragma unroll
    for (int jj = 0; jj < 30; ++jj) {
        w1b[jj] = gW1[dd * 60 + 30 + jj];   // gW1[d][1][jj]
        wg2[jj] = gW2[dd * 30 + jj];
    }
    float gb2v = gb2[dd];

    float z[6];
#pragma unroll
    for (int d = 0; d < 6; ++d) z[d] = zsb[b * 6 + d];
    float pacc = 0.f;

#pragma unroll 1
    for (int k = 0; k < Tn - 1; ++k) {
        float t = ts[k];
        float dt = ts[k + 1] - t;
        const float* cp = ctx + ((size_t)(k + 1) * Bn + b) * 3;
        float c0 = cp[0], c1 = cp[1], c2 = cp[2];
        float dwv[6];
        const float* dwp = dWall + ((size_t)k * Bn + b) * 6;
#pragma unroll
        for (int d = 0; d < 6; ++d) dwv[d] = dwp[d];
        float A[30];
        const float* agp = ag + (k * 6 + dd) * 30;
#pragma unroll
        for (int jj = 0; jj < 30; ++jj) A[jj] = agp[jj];

        float zq = z[0];
        zq = (q == 1) ? z[1] : zq;
        zq = (q == 2) ? z[2] : zq;
        zq = (q == 3) ? z[3] : zq;
        zq = (q == 4) ? z[4] : zq;
        zq = (q == 5) ? z[5] : zq;

        // f / h hidden layers (4 columns per lane)
        float fh[4], hh[4];
#pragma unroll
        for (int r = 0; r < 4; ++r) {
            float a = fmaf(t, wf[0][r], fb1v[r]);
#pragma unroll
            for (int i = 0; i < 6; ++i) a = fmaf(z[i], wf[1 + i][r], a);
            a = fmaf(c0, wf[7][r], a);
            a = fmaf(c1, wf[8][r], a);
            a = fmaf(c2, wf[9][r], a);
            fh[r] = sp_f(a);
            float ah = fmaf(t, wh[0][r], hb1v[r]);
#pragma unroll
            for (int i = 0; i < 6; ++i) ah = fmaf(z[i], wh[1 + i][r], ah);
            hh[r] = sp_f(ah);
        }
        // layer-2 partials + 8-lane butterfly reduce
        float pf[6], ph[6];
#pragma unroll
        for (int d = 0; d < 6; ++d) {
            float a = fh[0] * wf2[0][d];
            a = fmaf(fh[1], wf2[1][d], a);
            a = fmaf(fh[2], wf2[2][d], a);
            a = fmaf(fh[3], wf2[3][d], a);
            pf[d] = a;
            float ahh = hh[0] * wh2[0][d];
            ahh = fmaf(hh[1], wh2[1][d], ahh);
            ahh = fmaf(hh[2], wh2[2][d], ahh);
            ahh = fmaf(hh[3], wh2[3][d], ahh);
            ph[d] = ahh;
        }
#pragma unroll
        for (int mm = 1; mm <= 4; mm <<= 1) {
#pragma unroll
            for (int d = 0; d < 6; ++d) {
                pf[d] += __shfl_xor(pf[d], mm);
                ph[d] += __shfl_xor(ph[d], mm);
            }
        }
        float fv[6], hv[6];
#pragma unroll
        for (int d = 0; d < 6; ++d) { fv[d] = pf[d] + fb2v[d]; hv[d] = ph[d] + hb2v[d]; }

        // g for this lane's latent dim (lanes 0..5 carry the real values)
        float gacc = gb2v;
#pragma unroll
        for (int jj = 0; jj < 30; ++jj) {
            float a = fmaf(zq, w1b[jj], A[jj]);
            gacc = fmaf(sp_f(a), wg2[jj], gacc);
        }
        float eg = __expf(-fabsf(gacc));                       // stable sigmoid
        float gval = (gacc >= 0.f) ? 1.f / (1.f + eg) : eg / (1.f + eg);
        float gl[6];
#pragma unroll
        for (int d = 0; d < 6; ++d) gl[d] = __shfl(gval, d, 8);

        float s2 = 0.f;
#pragma unroll
        for (int d = 0; d < 6; ++d) {
            float u = (fv[d] - hv[d]) / gl[d];
            s2 = fmaf(u, u, s2);
        }
        pacc = fmaf(0.5f * dt, s2, pacc);
#pragma unroll
        for (int d = 0; d < 6; ++d)
            z[d] = fmaf(gl[d], dwv[d], fmaf(fv[d], dt, z[d]));

        if (q == 0) {
            float* zp = zsb + ((size_t)(k + 1) * Bn + b) * 6;
            zp[0] = z[0]; zp[1] = z[1]; zp[2] = z[2];
            zp[3] = z[3]; zp[4] = z[4]; zp[5] = z[5];
        }
    }
    // pacc is group-uniform; sum the 8 groups of this wave
    pacc += __shfl_xor(pacc, 8);
    pacc += __shfl_xor(pacc, 16);
    pacc += __shfl_xor(pacc, 32);
    if (tid == 0) atomicAdd(&acc[2], pacc);
}

// ------------------------------------------------------ decoder + likelihood
__global__ __launch_bounds__(256) void dec_kernel(
    const float* __restrict__ zsb, const float* __restrict__ xs,
    const float* __restrict__ dcW1, const float* __restrict__ dcb1,
    const float* __restrict__ dcW2, const float* __restrict__ dcb2,
    const float* __restrict__ dcW3, const float* __restrict__ dcb3,
    float* __restrict__ acc)
{
    __shared__ float w[4240];
    // dcW1 @0(180), dcb1 @180(30), dcW2 @210(900), dcb2 @1110(30),
    // dcW3 transposed @1140(3000): w3T[j3][j2], dcb3 @4140(100)
    for (int i = threadIdx.x; i < 180; i += 256) w[i] = dcW1[i];
    if (threadIdx.x < 30) w[180 + threadIdx.x] = dcb1[threadIdx.x];
    for (int i = threadIdx.x; i < 900; i += 256) w[210 + i] = dcW2[i];
    if (threadIdx.x < 30) w[1110 + threadIdx.x] = dcb2[threadIdx.x];
    for (int i = threadIdx.x; i < 3000; i += 256) {
        int j2 = i / 100, j3 = i % 100;
        w[1140 + j3 * 30 + j2] = dcW3[i];
    }
    for (int i = threadIdx.x; i < 100; i += 256) w[4140 + i] = dcb3[i];
    __syncthreads();

    int gid = blockIdx.x * 256 + threadIdx.x;       // = t*Bn + b
    const float* zp = zsb + (size_t)gid * 6;
    float zv[6];
#pragma unroll
    for (int i = 0; i < 6; ++i) zv[i] = zp[i];

    float h1[30];
#pragma unroll
    for (int j = 0; j < 30; ++j) h1[j] = w[180 + j];
#pragma unroll
    for (int i = 0; i < 6; ++i) {
        float zi = zv[i];
#pragma unroll
        for (int j = 0; j < 30; ++j) h1[j] = fmaf(zi, w[i * 30 + j], h1[j]);
    }
#pragma unroll
    for (int j = 0; j < 30; ++j) h1[j] = sp_f(h1[j]);

    float h2[30];
#pragma unroll
    for (int j = 0; j < 30; ++j) h2[j] = w[1110 + j];
    for (int j1 = 0; j1 < 30; ++j1) {
        float hv = h1[j1];
#pragma unroll
        for (int j = 0; j < 30; ++j) h2[j] = fmaf(hv, w[210 + j1 * 30 + j], h2[j]);
    }
#pragma unroll
    for (int j = 0; j < 30; ++j) h2[j] = sp_f(h2[j]);

    const float* tg = xs + (size_t)gid * 150 + 100;   // xs[:,:,-1,:]
    float lpacc = 0.f;
    for (int ff = 0; ff < 50; ++ff) {
        float xm = w[4140 + ff], xl = w[4140 + 50 + ff];
#pragma unroll
        for (int j2 = 0; j2 < 30; ++j2) {
            xm = fmaf(h2[j2], w[1140 + ff * 30 + j2], xm);
            xl = fmaf(h2[j2], w[1140 + (50 + ff) * 30 + j2], xl);
        }
        float cl = clamp6(xl);                 // log(xsig) == clipped xl
        float u = (tg[ff] - xm) * __expf(-cl);
        lpacc += -0.5f * u * u - cl - 0.91893853320467274f;   // 0.5*log(2*pi)
    }
#pragma unroll
    for (int mm = 1; mm <= 32; mm <<= 1) lpacc += __shfl_xor(lpacc, mm);
    __shared__ float red[4];
    if ((threadIdx.x & 63) == 0) red[threadIdx.x >> 6] = lpacc;
    __syncthreads();
    if (threadIdx.x == 0) atomicAdd(&acc[0], red[0] + red[1] + red[2] + red[3]);
}

__global__ void final_kernel(const float* __restrict__ acc, float* __restrict__ out)
{
    out[0] = acc[0] * (1.f / (float)Bn);
    out[1] = (acc[1] + acc[2]) * (1.f / (float)Bn);
}

// --------------------------------------------------------------------- launch
extern "C" void kernel_launch(void* const* d_in, const int* in_sizes, int n_in,
                              void* d_out, int out_size, void* d_ws, size_t ws_size,
                              hipStream_t stream)
{
    const float* xs   = (const float*)d_in[0];
    const float* ts   = (const float*)d_in[1];
    const float* eps0 = (const float*)d_in[2];
    const float* dW   = (const float*)d_in[3];
    const float* eW1  = (const float*)d_in[4];
    const float* eb1  = (const float*)d_in[5];
    const float* eW2  = (const float*)d_in[6];
    const float* eb2  = (const float*)d_in[7];
    const float* eW3  = (const float*)d_in[8];
    const float* eb3  = (const float*)d_in[9];
    const float* dcW1 = (const float*)d_in[10];
    const float* dcb1 = (const float*)d_in[11];
    const float* dcW2 = (const float*)d_in[12];
    const float* dcb2 = (const float*)d_in[13];
    const float* dcW3 = (const float*)d_in[14];
    const float* dcb3 = (const float*)d_in[15];
    const float* fW1  = (const float*)d_in[16];
    const float* fb1  = (const float*)d_in[17];
    const float* fW2  = (const float*)d_in[18];
    const float* fb2  = (const float*)d_in[19];
    const float* hW1  = (const float*)d_in[20];
    const float* hb1  = (const float*)d_in[21];
    const float* hW2  = (const float*)d_in[22];
    const float* hb2  = (const float*)d_in[23];
    const float* gW1  = (const float*)d_in[24];
    const float* gb1  = (const float*)d_in[25];
    const float* gW2  = (const float*)d_in[26];
    const float* gb2  = (const float*)d_in[27];
    const float* pm   = (const float*)d_in[28];
    const float* ps   = (const float*)d_in[29];

    float* ws  = (float*)d_ws;
    float* acc = ws;                    // [0]=S_lp, [1]=S_kl, [2]=S_path
    float* ctx = ws + 16;               // T*B*3 = 614400
    float* qm  = ctx + 614400;          // B*6
    float* qs  = qm + 12288;            // B*6
    float* zs  = qs + 12288;            // T*B*6 = 1228800
    float* ag  = zs + 1228800;          // 99*6*30 = 17820
    float* out = (float*)d_out;

    hipMemsetAsync(acc, 0, 16 * sizeof(float), stream);
    enc_kernel<<<800, 256, 0, stream>>>(xs, eW1, eb1, eW2, eb2, eW3, eb3, ctx, qm, qs);
    ag_kernel<<<70, 256, 0, stream>>>(ts, gW1, gb1, ag);
    z0kl_kernel<<<48, 256, 0, stream>>>(qm, qs, eps0, pm, ps, zs, acc);
    scan_kernel<<<256, 64, 0, stream>>>(ts, dW, fW1, fb1, fW2, fb2, hW1, hb1,
                                        hW2, hb2, gW1, gW2, gb2, ctx, ag, zs, acc);
    dec_kernel<<<800, 256, 0, stream>>>(zs, xs, dcW1, dcb1, dcW2, dcb2, dcW3, dcb3, acc);
    final_kernel<<<1, 1, 0, stream>>>(acc, out);
}

// Round 2
// 439.047 us; speedup vs baseline: 1.0161x; 1.0161x over previous
//
#include <hip/hip_runtime.h>
#include <hip/hip_bf16.h>
#include <math.h>

#define Tn 100
#define Bn 2048

__device__ __forceinline__ float sp_f(float x) {
    // jax.nn.softplus(x) = max(x,0) + log1p(exp(-|x|))
    float e = __expf(-fabsf(x));
    return fmaxf(x, 0.f) + __logf(1.f + e);
}
__device__ __forceinline__ float clamp6(float x) {
    return fminf(fmaxf(x, -6.f), 6.f);
}
// lane ^= 1 / lane ^= 2 within quads — pure VALU (no LDS pipe)
__device__ __forceinline__ float dpp_xor1(float x) {
    return __int_as_float(__builtin_amdgcn_mov_dpp(__float_as_int(x), 0xB1, 0xF, 0xF, 1));
}
__device__ __forceinline__ float dpp_xor2(float x) {
    return __int_as_float(__builtin_amdgcn_mov_dpp(__float_as_int(x), 0x4E, 0xF, 0xF, 1));
}
template <int OFF>
__device__ __forceinline__ float swz(float x) {
    return __int_as_float(__builtin_amdgcn_ds_swizzle(__float_as_int(x), OFF));
}

// ---------------------------------------------------------------- encoder
__global__ __launch_bounds__(256) void enc_kernel(
    const float* __restrict__ xs,
    const float* __restrict__ eW1, const float* __restrict__ eb1,
    const float* __restrict__ eW2, const float* __restrict__ eb2,
    const float* __restrict__ eW3, const float* __restrict__ eb3,
    float* __restrict__ ctx, float* __restrict__ qm, float* __restrict__ qs)
{
    __shared__ float w[5925];
    for (int i = threadIdx.x; i < 4500; i += 256) w[i] = eW1[i];
    if (threadIdx.x < 30) w[4500 + threadIdx.x] = eb1[threadIdx.x];
    for (int i = threadIdx.x; i < 900; i += 256) w[4530 + i] = eW2[i];
    if (threadIdx.x < 30) w[5430 + threadIdx.x] = eb2[threadIdx.x];
    for (int i = threadIdx.x; i < 450; i += 256) w[5460 + i] = eW3[i];
    if (threadIdx.x < 15) w[5910 + threadIdx.x] = eb3[threadIdx.x];
    __syncthreads();

    int gid = blockIdx.x * 256 + threadIdx.x;          // = tt*Bn + b
    const float* x = xs + (size_t)gid * 150;

    float h1[30];
#pragma unroll
    for (int j = 0; j < 30; ++j) h1[j] = w[4500 + j];
    for (int i = 0; i < 150; i += 2) {
        float2 xv = *reinterpret_cast<const float2*>(x + i);
#pragma unroll
        for (int j = 0; j < 30; ++j) h1[j] = fmaf(xv.x, w[i * 30 + j], h1[j]);
#pragma unroll
        for (int j = 0; j < 30; ++j) h1[j] = fmaf(xv.y, w[(i + 1) * 30 + j], h1[j]);
    }
#pragma unroll
    for (int j = 0; j < 30; ++j) h1[j] = sp_f(h1[j]);

    float h2[30];
#pragma unroll
    for (int j = 0; j < 30; ++j) h2[j] = w[5430 + j];
    for (int j1 = 0; j1 < 30; ++j1) {
        float hv = h1[j1];
#pragma unroll
        for (int j = 0; j < 30; ++j) h2[j] = fmaf(hv, w[4530 + j1 * 30 + j], h2[j]);
    }
#pragma unroll
    for (int j = 0; j < 30; ++j) h2[j] = sp_f(h2[j]);

    float o12 = w[5910 + 12], o13 = w[5910 + 13], o14 = w[5910 + 14];
#pragma unroll
    for (int j2 = 0; j2 < 30; ++j2) {
        o12 = fmaf(h2[j2], w[5460 + j2 * 15 + 12], o12);
        o13 = fmaf(h2[j2], w[5460 + j2 * 15 + 13], o13);
        o14 = fmaf(h2[j2], w[5460 + j2 * 15 + 14], o14);
    }
    float* cp = ctx + (size_t)gid * 3;
    cp[0] = o12; cp[1] = o13; cp[2] = o14;

    if (blockIdx.x < 8) {   // tt == 0
        int b = gid;
        float o[12];
#pragma unroll
        for (int j3 = 0; j3 < 12; ++j3) o[j3] = w[5910 + j3];
#pragma unroll
        for (int j2 = 0; j2 < 30; ++j2) {
            float hv = h2[j2];
#pragma unroll
            for (int j3 = 0; j3 < 12; ++j3) o[j3] = fmaf(hv, w[5460 + j2 * 15 + j3], o[j3]);
        }
#pragma unroll
        for (int d = 0; d < 6; ++d) { qm[b * 6 + d] = o[d]; qs[b * 6 + d] = o[6 + d]; }
    }
}

// ------------------------------------------- A_g precompute, padded stride 32
// ag[(k*6+d)*32 + jj] = gb1[d][jj] + ts[k] * gW1[d][0][jj]
__global__ void ag_kernel(const float* __restrict__ ts, const float* __restrict__ gW1,
                          const float* __restrict__ gb1, float* __restrict__ ag)
{
    int idx = blockIdx.x * 256 + threadIdx.x;
    if (idx >= (Tn - 1) * 180) return;
    int k = idx / 180, r = idx % 180;
    int d = r / 30, jj = r % 30;
    ag[(k * 6 + d) * 32 + jj] = fmaf(ts[k], gW1[d * 60 + jj], gb1[r]);
}

// ---------------------------------------------------------- z0 + KL reduction
__global__ __launch_bounds__(256) void z0kl_kernel(
    const float* __restrict__ qm, const float* __restrict__ qs,
    const float* __restrict__ eps0, const float* __restrict__ pm,
    const float* __restrict__ ps, float* __restrict__ zsb, float* __restrict__ acc)
{
    int idx = blockIdx.x * 256 + threadIdx.x;   // < Bn*6
    int d = idx % 6;
    float m = qm[idx], lsq = qs[idx];
    float sq = __expf(clamp6(lsq));
    zsb[idx] = fmaf(sq, eps0[idx], m);          // zs[0][b][d]
    float spz = __expf(clamp6(ps[d]));
    float dm = m - pm[d];
    float kl = __logf(spz / sq) + (sq * sq + dm * dm) / (2.f * spz * spz) - 0.5f;
#pragma unroll
    for (int mm = 1; mm <= 32; mm <<= 1) kl += __shfl_xor(kl, mm);
    __shared__ float red[4];
    if ((threadIdx.x & 63) == 0) red[threadIdx.x >> 6] = kl;
    __syncthreads();
    if (threadIdx.x == 0) atomicAdd(&acc[1], red[0] + red[1] + red[2] + red[3]);
}

// ------------------------------------------------------------------- SDE scan
// 8 lanes per chain, 1 wave per block, software-pipelined prefetch.
__global__ __launch_bounds__(64, 1) void scan_kernel(
    const float* __restrict__ ts, const float* __restrict__ dWall,
    const float* __restrict__ fW1, const float* __restrict__ fb1,
    const float* __restrict__ fW2, const float* __restrict__ fb2,
    const float* __restrict__ hW1, const float* __restrict__ hb1,
    const float* __restrict__ hW2, const float* __restrict__ hb2,
    const float* __restrict__ gW1, const float* __restrict__ gW2,
    const float* __restrict__ gb2,
    const float* __restrict__ ctx, const float* __restrict__ ag,
    float* __restrict__ zsb, float* __restrict__ acc)
{
    int tid = threadIdx.x;
    int q = tid & 7;
    int b = blockIdx.x * 8 + (tid >> 3);

    // --- per-lane weight registers -------------------------------------
    float wf[10][4], fb1v[4], wh[7][4], hb1v[4], wf2[4][6], wh2[4][6];
#pragma unroll
    for (int r = 0; r < 4; ++r) {
        int j = q + 8 * r;
        bool v = j < 30;
        fb1v[r] = v ? fb1[j] : 0.f;
        hb1v[r] = v ? hb1[j] : 0.f;
#pragma unroll
        for (int i = 0; i < 10; ++i) wf[i][r] = v ? fW1[i * 30 + j] : 0.f;
#pragma unroll
        for (int i = 0; i < 7; ++i) wh[i][r] = v ? hW1[i * 30 + j] : 0.f;
#pragma unroll
        for (int d = 0; d < 6; ++d) {
            wf2[r][d] = v ? fW2[j * 6 + d] : 0.f;
            wh2[r][d] = v ? hW2[j * 6 + d] : 0.f;
        }
    }
    float fb2v[6];
#pragma unroll
    for (int d = 0; d < 6; ++d) fb2v[d] = fb2[d];
    float hb2q = (q < 6) ? hb2[q] : 0.f;
    float wsel = (q < 6) ? 0.5f : 0.f;
    int dd = (q < 6) ? q : 0;
    float w1b[30], wg2[30];
#pragma unroll
    for (int jj = 0; jj < 30; ++jj) {
        w1b[jj] = gW1[dd * 60 + 30 + jj];   // gW1[d][1][jj]
        wg2[jj] = gW2[dd * 30 + jj];
    }
    float gb2v = gb2[dd];

    float z[6];
#pragma unroll
    for (int d = 0; d < 6; ++d) z[d] = zsb[b * 6 + d];
    float pacc = 0.f;

    // ---- prefetch step 0 ----------------------------------------------
    float tcur = ts[0], tnx = ts[1];
    float c0, c1, c2;
    { const float* cp = ctx + ((size_t)Bn + b) * 3; c0 = cp[0]; c1 = cp[1]; c2 = cp[2]; }
    float dwv[6];
    { const float* dwp = dWall + (size_t)b * 6;
      float2 w0 = *(const float2*)(dwp), w1 = *(const float2*)(dwp + 2), w2 = *(const float2*)(dwp + 4);
      dwv[0] = w0.x; dwv[1] = w0.y; dwv[2] = w1.x; dwv[3] = w1.y; dwv[4] = w2.x; dwv[5] = w2.y; }
    float A[30];
    { const float* ap = ag + dd * 32;
#pragma unroll
      for (int u4 = 0; u4 < 7; ++u4) {
          float4 v4 = *(const float4*)(ap + u4 * 4);
          A[u4 * 4 + 0] = v4.x; A[u4 * 4 + 1] = v4.y; A[u4 * 4 + 2] = v4.z; A[u4 * 4 + 3] = v4.w;
      }
      float2 v2 = *(const float2*)(ap + 28); A[28] = v2.x; A[29] = v2.y; }

#pragma unroll 2
    for (int k = 0; k < Tn - 1; ++k) {
        // ---- issue prefetch for k+1 (clamped dummy on last iter) ------
        int kn = (k < Tn - 2) ? (k + 1) : (Tn - 3);
        float tnn = ts[(k < Tn - 2) ? (k + 2) : (Tn - 1)];
        float cn0, cn1, cn2;
        { const float* cp = ctx + ((size_t)(kn + 1) * Bn + b) * 3;
          cn0 = cp[0]; cn1 = cp[1]; cn2 = cp[2]; }
        float dwn[6];
        { const float* dwp = dWall + ((size_t)kn * Bn + b) * 6;
          float2 w0 = *(const float2*)(dwp), w1 = *(const float2*)(dwp + 2), w2 = *(const float2*)(dwp + 4);
          dwn[0] = w0.x; dwn[1] = w0.y; dwn[2] = w1.x; dwn[3] = w1.y; dwn[4] = w2.x; dwn[5] = w2.y; }
        float An[30];
        { const float* ap = ag + (kn * 6 + dd) * 32;
#pragma unroll
          for (int u4 = 0; u4 < 7; ++u4) {
              float4 v4 = *(const float4*)(ap + u4 * 4);
              An[u4 * 4 + 0] = v4.x; An[u4 * 4 + 1] = v4.y; An[u4 * 4 + 2] = v4.z; An[u4 * 4 + 3] = v4.w;
          }
          float2 v2 = *(const float2*)(ap + 28); An[28] = v2.x; An[29] = v2.y; }

        float dt = tnx - tcur;
        float zq = z[0];
        zq = (q == 1) ? z[1] : zq;
        zq = (q == 2) ? z[2] : zq;
        zq = (q == 3) ? z[3] : zq;
        zq = (q == 4) ? z[4] : zq;
        zq = (q == 5) ? z[5] : zq;

        // ---- g hidden pre-activations (independent of f/h path) -------
        float gsp[30];
#pragma unroll
        for (int jj = 0; jj < 30; ++jj)
            gsp[jj] = sp_f(fmaf(zq, w1b[jj], A[jj]));

        // ---- f / h hidden layers --------------------------------------
        float fh[4], hh[4];
#pragma unroll
        for (int r = 0; r < 4; ++r) {
            float a = fmaf(tcur, wf[0][r], fb1v[r]);
#pragma unroll
            for (int i = 0; i < 6; ++i) a = fmaf(z[i], wf[1 + i][r], a);
            a = fmaf(c0, wf[7][r], a);
            a = fmaf(c1, wf[8][r], a);
            a = fmaf(c2, wf[9][r], a);
            fh[r] = sp_f(a);
            float ah = fmaf(tcur, wh[0][r], hb1v[r]);
#pragma unroll
            for (int i = 0; i < 6; ++i) ah = fmaf(z[i], wh[1 + i][r], ah);
            hh[r] = sp_f(ah);
        }
        // ---- layer-2 partials -----------------------------------------
        float pf[6], ph[6];
#pragma unroll
        for (int d = 0; d < 6; ++d) {
            float a = fh[0] * wf2[0][d];
            a = fmaf(fh[1], wf2[1][d], a);
            a = fmaf(fh[2], wf2[2][d], a);
            a = fmaf(fh[3], wf2[3][d], a);
            pf[d] = a;
            float e2 = hh[0] * wh2[0][d];
            e2 = fmaf(hh[1], wh2[1][d], e2);
            e2 = fmaf(hh[2], wh2[2][d], e2);
            e2 = fmaf(hh[3], wh2[3][d], e2);
            ph[d] = e2;
        }
        // ---- gacc (2 chains) — scheduler can overlap with butterflies -
        float ga0 = gb2v, ga1 = 0.f;
#pragma unroll
        for (int jj = 0; jj < 30; jj += 2) {
            ga0 = fmaf(gsp[jj], wg2[jj], ga0);
            ga1 = fmaf(gsp[jj + 1], wg2[jj + 1], ga1);
        }
        float gacc = ga0 + ga1;

        // ---- 8-lane butterfly: DPP, DPP, ds_swizzle -------------------
#pragma unroll
        for (int d = 0; d < 6; ++d) { pf[d] += dpp_xor1(pf[d]); ph[d] += dpp_xor1(ph[d]); }
#pragma unroll
        for (int d = 0; d < 6; ++d) { pf[d] += dpp_xor2(pf[d]); ph[d] += dpp_xor2(ph[d]); }
#pragma unroll
        for (int d = 0; d < 6; ++d) { pf[d] += swz<0x101F>(pf[d]); ph[d] += swz<0x101F>(ph[d]); }

        // ---- sigmoid + reciprocals ------------------------------------
        float eg = __expf(-fabsf(gacc));
        float rden = __builtin_amdgcn_rcpf(1.f + eg);
        float gval = (gacc >= 0.f) ? rden : eg * rden;
        float rgq = __builtin_amdgcn_rcpf(gval);

        float fv[6];
#pragma unroll
        for (int d = 0; d < 6; ++d) fv[d] = pf[d] + fb2v[d];

        // own-dim u, private pacc (no per-step reduce)
        float fvq = fv[0], phq = ph[0];
        fvq = (q == 1) ? fv[1] : fvq;  phq = (q == 1) ? ph[1] : phq;
        fvq = (q == 2) ? fv[2] : fvq;  phq = (q == 2) ? ph[2] : phq;
        fvq = (q == 3) ? fv[3] : fvq;  phq = (q == 3) ? ph[3] : phq;
        fvq = (q == 4) ? fv[4] : fvq;  phq = (q == 4) ? ph[4] : phq;
        fvq = (q == 5) ? fv[5] : fvq;  phq = (q == 5) ? ph[5] : phq;
        float uq = (fvq - (phq + hb2q)) * rgq;
        pacc = fmaf(wsel * dt, uq * uq, pacc);

        // broadcast g to all lanes of the 8-group
        float gl[6];
        gl[0] = swz<0x18>(gval); gl[1] = swz<0x38>(gval); gl[2] = swz<0x58>(gval);
        gl[3] = swz<0x78>(gval); gl[4] = swz<0x98>(gval); gl[5] = swz<0xB8>(gval);
#pragma unroll
        for (int d = 0; d < 6; ++d)
            z[d] = fmaf(gl[d], dwv[d], fmaf(fv[d], dt, z[d]));

        if (q == 0) {
            float* zp = zsb + ((size_t)(k + 1) * Bn + b) * 6;
            *(float2*)(zp)     = make_float2(z[0], z[1]);
            *(float2*)(zp + 2) = make_float2(z[2], z[3]);
            *(float2*)(zp + 4) = make_float2(z[4], z[5]);
        }
        // ---- rotate prefetch buffers ----------------------------------
        tcur = tnx; tnx = tnn;
        c0 = cn0; c1 = cn1; c2 = cn2;
#pragma unroll
        for (int d = 0; d < 6; ++d) dwv[d] = dwn[d];
#pragma unroll
        for (int jj = 0; jj < 30; ++jj) A[jj] = An[jj];
    }
    // wave-wide sum of per-lane pacc
#pragma unroll
    for (int mm = 1; mm <= 32; mm <<= 1) pacc += __shfl_xor(pacc, mm);
    if (tid == 0) atomicAdd(&acc[2], pacc);
}

// ------------------------------------------------------ decoder + likelihood
__global__ __launch_bounds__(256) void dec_kernel(
    const float* __restrict__ zsb, const float* __restrict__ xs,
    const float* __restrict__ dcW1, const float* __restrict__ dcb1,
    const float* __restrict__ dcW2, const float* __restrict__ dcb2,
    const float* __restrict__ dcW3, const float* __restrict__ dcb3,
    float* __restrict__ acc)
{
    __shared__ float w[4240];
    for (int i = threadIdx.x; i < 180; i += 256) w[i] = dcW1[i];
    if (threadIdx.x < 30) w[180 + threadIdx.x] = dcb1[threadIdx.x];
    for (int i = threadIdx.x; i < 900; i += 256) w[210 + i] = dcW2[i];
    if (threadIdx.x < 30) w[1110 + threadIdx.x] = dcb2[threadIdx.x];
    for (int i = threadIdx.x; i < 3000; i += 256) {
        int j2 = i / 100, j3 = i % 100;
        w[1140 + j3 * 30 + j2] = dcW3[i];
    }
    for (int i = threadIdx.x; i < 100; i += 256) w[4140 + i] = dcb3[i];
    __syncthreads();

    int gid = blockIdx.x * 256 + threadIdx.x;       // = t*Bn + b
    const float* zp = zsb + (size_t)gid * 6;
    float zv[6];
#pragma unroll
    for (int i = 0; i < 6; ++i) zv[i] = zp[i];

    float h1[30];
#pragma unroll
    for (int j = 0; j < 30; ++j) h1[j] = w[180 + j];
#pragma unroll
    for (int i = 0; i < 6; ++i) {
        float zi = zv[i];
#pragma unroll
        for (int j = 0; j < 30; ++j) h1[j] = fmaf(zi, w[i * 30 + j], h1[j]);
    }
#pragma unroll
    for (int j = 0; j < 30; ++j) h1[j] = sp_f(h1[j]);

    float h2[30];
#pragma unroll
    for (int j = 0; j < 30; ++j) h2[j] = w[1110 + j];
    for (int j1 = 0; j1 < 30; ++j1) {
        float hv = h1[j1];
#pragma unroll
        for (int j = 0; j < 30; ++j) h2[j] = fmaf(hv, w[210 + j1 * 30 + j], h2[j]);
    }
#pragma unroll
    for (int j = 0; j < 30; ++j) h2[j] = sp_f(h2[j]);

    const float* tg = xs + (size_t)gid * 150 + 100;   // xs[:,:,-1,:]
    float lpacc = 0.f;
    for (int ff = 0; ff < 50; ++ff) {
        float xm = w[4140 + ff], xl = w[4140 + 50 + ff];
#pragma unroll
        for (int j2 = 0; j2 < 30; ++j2) {
            xm = fmaf(h2[j2], w[1140 + ff * 30 + j2], xm);
            xl = fmaf(h2[j2], w[1140 + (50 + ff) * 30 + j2], xl);
        }
        float cl = clamp6(xl);
        float u = (tg[ff] - xm) * __expf(-cl);
        lpacc += -0.5f * u * u - cl - 0.91893853320467274f;
    }
#pragma unroll
    for (int mm = 1; mm <= 32; mm <<= 1) lpacc += __shfl_xor(lpacc, mm);
    __shared__ float red[4];
    if ((threadIdx.x & 63) == 0) red[threadIdx.x >> 6] = lpacc;
    __syncthreads();
    if (threadIdx.x == 0) atomicAdd(&acc[0], red[0] + red[1] + red[2] + red[3]);
}

__global__ void final_kernel(const float* __restrict__ acc, float* __restrict__ out)
{
    out[0] = acc[0] * (1.f / (float)Bn);
    out[1] = (acc[1] + acc[2]) * (1.f / (float)Bn);
}

// --------------------------------------------------------------------- launch
extern "C" void kernel_launch(void* const* d_in, const int* in_sizes, int n_in,
                              void* d_out, int out_size, void* d_ws, size_t ws_size,
                              hipStream_t stream)
{
    const float* xs   = (const float*)d_in[0];
    const float* ts   = (const float*)d_in[1];
    const float* eps0 = (const float*)d_in[2];
    const float* dW   = (const float*)d_in[3];
    const float* eW1  = (const float*)d_in[4];
    const float* eb1  = (const float*)d_in[5];
    const float* eW2  = (const float*)d_in[6];
    const float* eb2  = (const float*)d_in[7];
    const float* eW3  = (const float*)d_in[8];
    const float* eb3  = (const float*)d_in[9];
    const float* dcW1 = (const float*)d_in[10];
    const float* dcb1 = (const float*)d_in[11];
    const float* dcW2 = (const float*)d_in[12];
    const float* dcb2 = (const float*)d_in[13];
    const float* dcW3 = (const float*)d_in[14];
    const float* dcb3 = (const float*)d_in[15];
    const float* fW1  = (const float*)d_in[16];
    const float* fb1  = (const float*)d_in[17];
    const float* fW2  = (const float*)d_in[18];
    const float* fb2  = (const float*)d_in[19];
    const float* hW1  = (const float*)d_in[20];
    const float* hb1  = (const float*)d_in[21];
    const float* hW2  = (const float*)d_in[22];
    const float* hb2  = (const float*)d_in[23];
    const float* gW1  = (const float*)d_in[24];
    const float* gb1  = (const float*)d_in[25];
    const float* gW2  = (const float*)d_in[26];
    const float* gb2  = (const float*)d_in[27];
    const float* pm   = (const float*)d_in[28];
    const float* ps   = (const float*)d_in[29];

    float* ws  = (float*)d_ws;
    float* acc = ws;                    // [0]=S_lp, [1]=S_kl, [2]=S_path
    float* ctx = ws + 16;               // T*B*3 = 614400
    float* qm  = ctx + 614400;          // B*6
    float* qs  = qm + 12288;            // B*6
    float* zs  = qs + 12288;            // T*B*6 = 1228800
    float* ag  = zs + 1228800;          // 99*6*32 = 19008 (padded stride 32)
    float* out = (float*)d_out;

    hipMemsetAsync(acc, 0, 16 * sizeof(float), stream);
    enc_kernel<<<800, 256, 0, stream>>>(xs, eW1, eb1, eW2, eb2, eW3, eb3, ctx, qm, qs);
    ag_kernel<<<70, 256, 0, stream>>>(ts, gW1, gb1, ag);
    z0kl_kernel<<<48, 256, 0, stream>>>(qm, qs, eps0, pm, ps, zs, acc);
    scan_kernel<<<256, 64, 0, stream>>>(ts, dW, fW1, fb1, fW2, fb2, hW1, hb1,
                                        hW2, hb2, gW1, gW2, gb2, ctx, ag, zs, acc);
    dec_kernel<<<800, 256, 0, stream>>>(zs, xs, dcW1, dcb1, dcW2, dcb2, dcW3, dcb3, acc);
    final_kernel<<<1, 1, 0, stream>>>(acc, out);
}